// Round 11
// baseline (310.854 us; speedup 1.0000x reference)
//
#include <hip/hip_runtime.h>
#include <stdint.h>

typedef __bf16 bf16_t;
typedef bf16_t bf16x4 __attribute__((ext_vector_type(4)));
typedef bf16_t bf16x8 __attribute__((ext_vector_type(8)));
typedef float f32x4 __attribute__((ext_vector_type(4)));

#define DIM 256
#define NNODES 50000

// ---------------- edge dtype detection (int64 vs int32), per-wave inline ----------------
__device__ __forceinline__ int detect_f64(const int* __restrict__ ei) {
    int v = ei[2 * (threadIdx.x & 63) + 1];
    unsigned long long m = __ballot(v == 0);
    return __popcll(m) > 32;
}

__device__ __forceinline__ int load_edge(const int* __restrict__ ei, int E, int f64,
                                         int which /*0=src,1=dst*/, int e) {
    int v = f64 ? ei[(size_t)which * 2 * E + 2 * (size_t)e]   // int64 low word (LE)
                : ei[(size_t)which * E + (size_t)e];
    return min(max(v, 0), NNODES - 1);
}

// ---------------- prep: zero counts + convert W (fp32 -> half-major fragment order) -------
// New Wf layout (half-major so a 64KB column-half stages as ONE contiguous copy):
//   half = nt>>3 (cols half*128..), flat short index:
//   half*32768 + s*4096 + (nt&7)*512 + (quad*16+m)*8 + j
// where k = s*32+quad*8+j, n = nt*16+m.
__global__ __launch_bounds__(256) void prep_kernel(int* __restrict__ counts,
                                                   const float* __restrict__ W1,
                                                   const float* __restrict__ W2,
                                                   bf16_t* __restrict__ Wf1,
                                                   bf16_t* __restrict__ Wf2, int n) {
    const int nb = (NNODES + 255) / 256;   // 196
    int b = blockIdx.x, t = threadIdx.x;
    if (b < nb) {
        int idx = b * 256 + t;
        if (idx < n) counts[idx] = 0;
    } else {
        int cw = b - nb;                   // 0..511
        const float* W = (cw & 256) ? W2 : W1;
        bf16_t* Wf = (cw & 256) ? Wf2 : Wf1;
        int k = cw & 255;
        int s = k >> 5, quad = (k >> 3) & 3, j = k & 7;
        int nt = t >> 4, m = t & 15;
        int half = nt >> 3, nt7 = nt & 7;
        Wf[half * 32768 + s * 4096 + nt7 * 512 + (quad * 16 + m) * 8 + j] =
            (bf16_t)W[k * DIM + t];
    }
}

// ---------------- hist ----------------
__global__ void hist_kernel(const int* __restrict__ ei, int E, int* __restrict__ counts) {
    int f64 = detect_f64(ei);
    int e = blockIdx.x * blockDim.x + threadIdx.x;
    if (e < E) atomicAdd(&counts[load_edge(ei, E, f64, 1, e)], 1);
}

// ---------------- one-dispatch scan, zero synchronization (r9, passed) ----------------
__global__ __launch_bounds__(256) void scan_kernel(const int* __restrict__ counts,
                                                   int* __restrict__ offsets,
                                                   int* __restrict__ cursor,
                                                   float* __restrict__ dinv, int n) {
    __shared__ int red[256];
    __shared__ int sm[256];
    int b = blockIdx.x, t = threadIdx.x;

    int part = 0;
    const int4* c4 = (const int4*)counts;
    int lim = b * 64;
    for (int j = t; j < lim; j += 256) {
        int4 v = c4[j];
        part += v.x + v.y + v.z + v.w;
    }
    red[t] = part;
    __syncthreads();
    #pragma unroll
    for (int off = 128; off > 0; off >>= 1) {
        if (t < off) red[t] += red[t + off];
        __syncthreads();
    }
    int base = red[0];

    int idx = b * 256 + t;
    int v = (idx < n) ? counts[idx] : 0;
    sm[t] = v;
    __syncthreads();
    #pragma unroll
    for (int off = 1; off < 256; off <<= 1) {
        int u = (t >= off) ? sm[t - off] : 0;
        __syncthreads();
        sm[t] += u;
        __syncthreads();
    }
    if (idx < n) {
        int incl = base + sm[t];
        offsets[idx + 1] = incl;
        cursor[idx] = incl - v;
        dinv[idx] = rsqrtf((float)(v + 1));  // +1 self-loop
    }
    if (idx == 0) offsets[0] = 0;
}

// ---------------- scatter (standalone) ----------------
__global__ void scatter_kernel(const int* __restrict__ ei, int E,
                               const float* __restrict__ dinv, int* __restrict__ cursor,
                               int2* __restrict__ csr_e) {
    int f64 = detect_f64(ei);
    int e = blockIdx.x * blockDim.x + threadIdx.x;
    if (e < E) {
        int s = load_edge(ei, E, f64, 0, e);
        int d = load_edge(ei, E, f64, 1, e);
        int pos = atomicAdd(&cursor[d], 1);
        if (pos >= 0 && pos < E) {
            int2 v;
            v.x = s;
            v.y = __float_as_int(dinv[s] * dinv[d]);
            csr_e[pos] = v;
        }
    }
}

// ---------------- GEMM: W-half resident in LDS, persistent waves, no inner barriers ------
// grid (256, 2): blockIdx.y = column half. Block stages its 64KB half of W ONCE (one
// barrier), then each wave loops row-tiles (tile += 1024) reading A from global and B from
// LDS -- zero re-staging, zero main-loop barriers (r10's 44us GEMM spent itself on 50MB of
// redundant W staging + 2 barriers/slice at 1.5 waves/SIMD). 512 blocks = 2/CU (LDS-bound).
// acc = 8 x f32x4 = 32 VGPR. A is read once per half (2x total; concurrent halves share L3).

template <bool F32A>
__global__ __launch_bounds__(256, 2) void gemm_kernel(const void* __restrict__ Xv,
                                                      const bf16_t* __restrict__ Wf,
                                                      bf16_t* __restrict__ H, int tiles) {
    __shared__ bf16_t sB[32768];              // 64KB: one column-half of W, all 8 slices
    int tid = threadIdx.x;
    int half = blockIdx.y;

    {
        const bf16x8* g = (const bf16x8*)(Wf + half * 32768);
        bf16x8* d = (bf16x8*)sB;
        #pragma unroll
        for (int it = 0; it < 16; it++) d[tid + it * 256] = g[tid + it * 256];
    }
    __syncthreads();                          // the only barrier

    int wave = tid >> 6, lane = tid & 63;
    int m = lane & 15, quad = lane >> 4;
    int wid = blockIdx.x * 4 + wave;          // 0..1023
    int hbase = half * 128;

    for (int tile = wid; tile < tiles; tile += 1024) {
        int arow = tile * 16 + m;             // exact: 50000 = 3125*16, no clamp needed
        f32x4 acc[8] = {};

        #pragma unroll
        for (int s = 0; s < 8; s++) {
            bf16x8 a;
            if (F32A) {
                const f32x4* xp = (const f32x4*)((const float*)Xv + (size_t)arow * DIM + s * 32 + quad * 8);
                f32x4 x0 = xp[0], x1 = xp[1];
                #pragma unroll
                for (int j = 0; j < 4; j++) { a[j] = (bf16_t)x0[j]; a[j + 4] = (bf16_t)x1[j]; }
            } else {
                a = *(const bf16x8*)((const bf16_t*)Xv + (size_t)arow * DIM + s * 32 + quad * 8);
            }
            const bf16_t* bs = sB + s * 4096;
            #pragma unroll
            for (int nt = 0; nt < 8; nt++) {
                bf16x8 b = *(const bf16x8*)(bs + nt * 512 + lane * 8);  // sequential: no conflicts
                acc[nt] = __builtin_amdgcn_mfma_f32_16x16x32_bf16(a, b, acc[nt], 0, 0, 0);
            }
        }

        int rowb = tile * 16 + quad * 4;
        #pragma unroll
        for (int nt = 0; nt < 8; nt++) {
            #pragma unroll
            for (int r = 0; r < 4; r++) {
                H[(size_t)(rowb + r) * DIM + hbase + nt * 16 + m] = (bf16_t)acc[nt][r];
            }
        }
    }
}

// ---------------- Aggregation (r10 version: 8-deep fenced gathers, masked tail) ----------
template <int OUT_BF16>
__global__ __launch_bounds__(256) void aggregate_kernel(const bf16_t* __restrict__ H,
                                                        const int* __restrict__ offsets,
                                                        const int2* __restrict__ csr_e,
                                                        const float* __restrict__ dinv,
                                                        const float* __restrict__ bias,
                                                        void* __restrict__ outv, int n) {
    int wg = threadIdx.x >> 5;     // 8 node-groups per block
    int l = threadIdx.x & 31;      // lane in group: dims l*8 .. l*8+7
    int i = blockIdx.x * 8 + wg;
    if (i >= n) return;

    const char* Hb = (const char*)H;
    int doff = l * 16;

    auto cvt = [](bf16x4 v) -> f32x4 {
        f32x4 r;
        #pragma unroll
        for (int j = 0; j < 4; j++) r[j] = (float)v[j];
        return r;
    };
    auto lo4 = [](bf16x8 v) -> bf16x4 { return __builtin_shufflevector(v, v, 0, 1, 2, 3); };
    auto hi4 = [](bf16x8 v) -> bf16x4 { return __builtin_shufflevector(v, v, 4, 5, 6, 7); };

    float dii = dinv[i];
    bf16x8 selfv = *(const bf16x8*)(Hb + ((size_t)i << 9) + doff);
    f32x4 acc0 = cvt(lo4(selfv)) * (dii * dii);
    f32x4 acc1 = cvt(hi4(selfv)) * (dii * dii);

    int e0 = offsets[i], e1 = offsets[i + 1];
    int e = e0;
    for (; e + 8 <= e1; e += 8) {
        unsigned s[8]; float w[8];
        #pragma unroll
        for (int j = 0; j < 8; j++) {
            int2 t = csr_e[e + j];
            s[j] = min((unsigned)t.x, (unsigned)(NNODES - 1));
            w[j] = __int_as_float(t.y);
        }
        bf16x8 h[8];
        #pragma unroll
        for (int j = 0; j < 8; j++) {
            h[j] = *(const bf16x8*)(Hb + ((size_t)s[j] << 9) + doff);
        }
        __builtin_amdgcn_sched_barrier(0);   // all 8 gathers issued before any consume
        #pragma unroll
        for (int j = 0; j < 8; j++) {
            acc0 += cvt(lo4(h[j])) * w[j];
            acc1 += cvt(hi4(h[j])) * w[j];
        }
    }
    if (e < e1) {
        bf16x8 z;
        #pragma unroll
        for (int q = 0; q < 8; q++) z[q] = (bf16_t)0.0f;
        unsigned s[8]; float w[8]; bool val[8];
        #pragma unroll
        for (int j = 0; j < 8; j++) {
            bool valid = (e + j) < e1;
            val[j] = valid;
            int2 t = csr_e[valid ? e + j : e];   // e < e1 so csr_e[e] is safe
            s[j] = min((unsigned)t.x, (unsigned)(NNODES - 1));
            w[j] = valid ? __int_as_float(t.y) : 0.0f;
        }
        bf16x8 h[8];
        #pragma unroll
        for (int j = 0; j < 8; j++) {
            h[j] = z;
            if (val[j]) h[j] = *(const bf16x8*)(Hb + ((size_t)s[j] << 9) + doff);
        }
        __builtin_amdgcn_sched_barrier(0);
        #pragma unroll
        for (int j = 0; j < 8; j++) {
            acc0 += cvt(lo4(h[j])) * w[j];
            acc1 += cvt(hi4(h[j])) * w[j];
        }
    }

    const f32x4* bp = (const f32x4*)(bias + l * 8);
    acc0 += bp[0];
    acc1 += bp[1];
    #pragma unroll
    for (int j = 0; j < 4; j++) {
        acc0[j] = fmaxf(acc0[j], 0.0f);
        acc1[j] = fmaxf(acc1[j], 0.0f);
    }

    if (OUT_BF16) {
        bf16x8 o;
        #pragma unroll
        for (int j = 0; j < 4; j++) { o[j] = (bf16_t)acc0[j]; o[j + 4] = (bf16_t)acc1[j]; }
        *(bf16x8*)((bf16_t*)outv + (size_t)i * DIM + l * 8) = o;
    } else {
        float* op = (float*)outv + (size_t)i * DIM + l * 8;
        *(f32x4*)op = acc0;
        *(f32x4*)(op + 4) = acc1;
    }
}

// ---------------- launch ----------------

extern "C" void kernel_launch(void* const* d_in, const int* in_sizes, int n_in,
                              void* d_out, int out_size, void* d_ws, size_t ws_size,
                              hipStream_t stream) {
    const float* x  = (const float*)d_in[0];
    const int*   ei = (const int*)d_in[1];
    const float* W1 = (const float*)d_in[2];
    const float* b1 = (const float*)d_in[3];
    const float* W2 = (const float*)d_in[4];
    const float* b2 = (const float*)d_in[5];
    float* out = (float*)d_out;

    const int n = NNODES;
    const int E = in_sizes[1] / 2;
    const int nb = (n + 255) / 256;            // 196

    char* ws = (char*)d_ws;
    size_t off = 0;
    auto alloc = [&](size_t bytes) -> char* {
        char* p = ws + off;
        off += (bytes + 255) & ~(size_t)255;
        return p;
    };
    float*  dinv     = (float*)alloc((size_t)n * 4);
    int*    counts   = (int*)alloc((size_t)n * 4);
    int*    offsets  = (int*)alloc((size_t)(n + 1) * 4);
    int*    cursor   = (int*)alloc((size_t)n * 4);
    int2*   csr_e    = (int2*)alloc((size_t)E * 8);
    bf16_t* Wf1      = (bf16_t*)alloc((size_t)DIM * DIM * 2);
    bf16_t* Wf2      = (bf16_t*)alloc((size_t)DIM * DIM * 2);
    bf16_t* P        = (bf16_t*)alloc((size_t)n * DIM * 2);   // GEMM output (bf16, row-major)
    bf16_t* X2       = (bf16_t*)alloc((size_t)n * DIM * 2);   // inter-layer activation (bf16)

    int tiles = (n + 15) / 16;                 // 3125 (exact: 50000 = 16*3125)
    int hist_blocks = (E + 255) / 256;         // 1563
    int agg_blocks = (n + 7) / 8;              // 6250
    dim3 gemm_grid(256, 2);                    // 512 blocks, 2/CU (64KB LDS each)

    // 1: zero counts + convert both W (half-major fragment layout)
    prep_kernel<<<nb + 512, 256, 0, stream>>>(counts, W1, W2, Wf1, Wf2, n);
    // 2-4: CSR chain
    hist_kernel<<<hist_blocks, 256, 0, stream>>>(ei, E, counts);
    scan_kernel<<<nb, 256, 0, stream>>>(counts, offsets, cursor, dinv, n);
    scatter_kernel<<<hist_blocks, 256, 0, stream>>>(ei, E, dinv, cursor, csr_e);
    // 5-8: gemm1, agg1, gemm2, agg2
    gemm_kernel<true><<<gemm_grid, 256, 0, stream>>>(x, Wf1, P, tiles);
    aggregate_kernel<1><<<agg_blocks, 256, 0, stream>>>(P, offsets, csr_e, dinv, b1, X2, n);
    gemm_kernel<false><<<gemm_grid, 256, 0, stream>>>(X2, Wf2, P, tiles);
    aggregate_kernel<0><<<agg_blocks, 256, 0, stream>>>(P, offsets, csr_e, dinv, b2, out, n);
}

// Round 12
// 251.458 us; speedup vs baseline: 1.2362x; 1.2362x over previous
//
#include <hip/hip_runtime.h>
#include <stdint.h>

typedef __bf16 bf16_t;
typedef bf16_t bf16x4 __attribute__((ext_vector_type(4)));
typedef bf16_t bf16x8 __attribute__((ext_vector_type(8)));
typedef float f32x4 __attribute__((ext_vector_type(4)));

#define DIM 256
#define NNODES 50000

// ---------------- edge dtype detection (int64 vs int32), per-wave inline ----------------
__device__ __forceinline__ int detect_f64(const int* __restrict__ ei) {
    int v = ei[2 * (threadIdx.x & 63) + 1];
    unsigned long long m = __ballot(v == 0);
    return __popcll(m) > 32;
}

__device__ __forceinline__ int load_edge(const int* __restrict__ ei, int E, int f64,
                                         int which /*0=src,1=dst*/, int e) {
    int v = f64 ? ei[(size_t)which * 2 * E + 2 * (size_t)e]   // int64 low word (LE)
                : ei[(size_t)which * E + (size_t)e];
    return min(max(v, 0), NNODES - 1);
}

// ---------------- prep: zero counts + convert W (fp32 -> fragment-order bf16) ----------
// Wf layout (r9): slice s=k>>5; frag f=nt*64+quad*16+m; flat short index s*8192+f*8+j.
__global__ __launch_bounds__(256) void prep_kernel(int* __restrict__ counts,
                                                   const float* __restrict__ W1,
                                                   const float* __restrict__ W2,
                                                   bf16_t* __restrict__ Wf1,
                                                   bf16_t* __restrict__ Wf2, int n) {
    const int nb = (NNODES + 255) / 256;   // 196
    int b = blockIdx.x, t = threadIdx.x;
    if (b < nb) {
        int idx = b * 256 + t;
        if (idx < n) counts[idx] = 0;
    } else {
        int cw = b - nb;                   // 0..511
        const float* W = (cw & 256) ? W2 : W1;
        bf16_t* Wf = (cw & 256) ? Wf2 : Wf1;
        int k = cw & 255;
        int s = k >> 5, quad = (k >> 3) & 3, j = k & 7;
        int nt = t >> 4, m = t & 15;
        Wf[s * 8192 + (nt * 64 + quad * 16 + m) * 8 + j] = (bf16_t)W[k * DIM + t];
    }
}

// ---------------- one-dispatch scan, zero synchronization (r9, passed) ----------------
__global__ __launch_bounds__(256) void scan_kernel(const int* __restrict__ counts,
                                                   int* __restrict__ offsets,
                                                   int* __restrict__ cursor,
                                                   float* __restrict__ dinv, int n) {
    __shared__ int red[256];
    __shared__ int sm[256];
    int b = blockIdx.x, t = threadIdx.x;

    int part = 0;
    const int4* c4 = (const int4*)counts;
    int lim = b * 64;
    for (int j = t; j < lim; j += 256) {
        int4 v = c4[j];
        part += v.x + v.y + v.z + v.w;
    }
    red[t] = part;
    __syncthreads();
    #pragma unroll
    for (int off = 128; off > 0; off >>= 1) {
        if (t < off) red[t] += red[t + off];
        __syncthreads();
    }
    int base = red[0];

    int idx = b * 256 + t;
    int v = (idx < n) ? counts[idx] : 0;
    sm[t] = v;
    __syncthreads();
    #pragma unroll
    for (int off = 1; off < 256; off <<= 1) {
        int u = (t >= off) ? sm[t - off] : 0;
        __syncthreads();
        sm[t] += u;
        __syncthreads();
    }
    if (idx < n) {
        int incl = base + sm[t];
        offsets[idx + 1] = incl;
        cursor[idx] = incl - v;
        dinv[idx] = rsqrtf((float)(v + 1));  // +1 self-loop
    }
    if (idx == 0) offsets[0] = 0;
}

// ---------------- scatter (standalone) ----------------
__global__ void scatter_kernel(const int* __restrict__ ei, int E,
                               const float* __restrict__ dinv, int* __restrict__ cursor,
                               int2* __restrict__ csr_e) {
    int f64 = detect_f64(ei);
    int e = blockIdx.x * blockDim.x + threadIdx.x;
    if (e < E) {
        int s = load_edge(ei, E, f64, 0, e);
        int d = load_edge(ei, E, f64, 1, e);
        int pos = atomicAdd(&cursor[d], 1);
        if (pos >= 0 && pos < E) {
            int2 v;
            v.x = s;
            v.y = __float_as_int(dinv[s] * dinv[d]);
            csr_e[pos] = v;
        }
    }
}

// ---------------- GEMM body: 1 tile/wave (r9 occupancy) + double-buffered W slices ------
// Per slice: issue next slice's global loads BEFORE compute, ds_write after compute, ONE
// barrier per slice (was 2 + full load->LDS round-trip stall). LDS 2x16KB = 32KB.
// r11 lesson: keep 782 blocks / 16 waves/CU -- TLP first, then pipeline.
template <bool F32A>
__device__ __forceinline__ void gemm_body(const void* __restrict__ Xv,
                                          const bf16_t* __restrict__ Wf,
                                          bf16_t* __restrict__ H, int tiles, int bid,
                                          bf16_t* sB /*[2][8192]*/) {
    int tid = threadIdx.x;
    int wave = tid >> 6, lane = tid & 63;
    int m = lane & 15, quad = lane >> 4;
    int tile = bid * 4 + wave;
    bool active = tile < tiles;
    int arow = (min(tile, tiles - 1)) * 16 + m;

    f32x4 acc[16] = {};

    // prologue: stage slice 0 into buffer 0
    {
        const bf16x8* g = (const bf16x8*)Wf;
        bf16x8* d = (bf16x8*)sB;
        #pragma unroll
        for (int it = 0; it < 4; it++) d[tid + it * 256] = g[tid + it * 256];
    }
    __syncthreads();

    for (int s = 0; s < 8; s++) {
        int cur = s & 1, nxt = cur ^ 1;

        // issue next slice's global loads (latency hides under this slice's compute)
        bf16x8 g0, g1, g2, g3;
        if (s < 7) {
            const bf16x8* g = (const bf16x8*)Wf + (s + 1) * 1024;
            g0 = g[tid]; g1 = g[tid + 256]; g2 = g[tid + 512]; g3 = g[tid + 768];
        }

        // A fragment: A[m][k = s*32 + quad*8 + j]
        bf16x8 a;
        if (F32A) {
            const f32x4* xp = (const f32x4*)((const float*)Xv + (size_t)arow * DIM + s * 32 + quad * 8);
            f32x4 x0 = xp[0], x1 = xp[1];
            #pragma unroll
            for (int j = 0; j < 4; j++) { a[j] = (bf16_t)x0[j]; a[j + 4] = (bf16_t)x1[j]; }
        } else {
            a = *(const bf16x8*)((const bf16_t*)Xv + (size_t)arow * DIM + s * 32 + quad * 8);
        }

        const bf16_t* bs = sB + cur * 8192;
        #pragma unroll
        for (int nt = 0; nt < 16; nt++) {
            bf16x8 b = *(const bf16x8*)(bs + nt * 512 + lane * 8);  // sequential: no conflicts
            acc[nt] = __builtin_amdgcn_mfma_f32_16x16x32_bf16(a, b, acc[nt], 0, 0, 0);
        }

        // write next slice into alternate buffer, then the slice barrier
        if (s < 7) {
            bf16x8* d = (bf16x8*)(sB + nxt * 8192);
            d[tid] = g0; d[tid + 256] = g1; d[tid + 512] = g2; d[tid + 768] = g3;
        }
        __syncthreads();
    }

    if (active) {
        int rowb = tile * 16 + quad * 4;
        #pragma unroll
        for (int nt = 0; nt < 16; nt++) {
            #pragma unroll
            for (int r = 0; r < 4; r++) {
                H[(size_t)(rowb + r) * DIM + nt * 16 + m] = (bf16_t)acc[nt][r];
            }
        }
    }
}

// ---------------- GEMM1 (fp32 A) + hist fused (r9: proven -6us) ----------------
__global__ __launch_bounds__(256, 4) void gemm1_hist_kernel(const float* __restrict__ X,
                                                            const bf16_t* __restrict__ Wf,
                                                            bf16_t* __restrict__ H, int tiles,
                                                            int gemm_blocks,
                                                            const int* __restrict__ ei, int E,
                                                            int* __restrict__ counts) {
    __shared__ bf16_t sB[2 * 8192];
    if ((int)blockIdx.x >= gemm_blocks) {
        int f64 = detect_f64(ei);
        int e = (blockIdx.x - gemm_blocks) * 256 + threadIdx.x;
        if (e < E) atomicAdd(&counts[load_edge(ei, E, f64, 1, e)], 1);
        return;
    }
    gemm_body<true>(X, Wf, H, tiles, blockIdx.x, sB);
}

// ---------------- GEMM layer 2 (bf16 A) ----------------
__global__ __launch_bounds__(256, 4) void gemm2_kernel(const bf16_t* __restrict__ Xv,
                                                       const bf16_t* __restrict__ Wf,
                                                       bf16_t* __restrict__ H, int tiles) {
    __shared__ bf16_t sB[2 * 8192];
    gemm_body<false>(Xv, Wf, H, tiles, blockIdx.x, sB);
}

// ---------------- Aggregation (r10: 8-deep fenced gathers, masked tail) ----------------
template <int OUT_BF16>
__global__ __launch_bounds__(256) void aggregate_kernel(const bf16_t* __restrict__ H,
                                                        const int* __restrict__ offsets,
                                                        const int2* __restrict__ csr_e,
                                                        const float* __restrict__ dinv,
                                                        const float* __restrict__ bias,
                                                        void* __restrict__ outv, int n) {
    int wg = threadIdx.x >> 5;     // 8 node-groups per block
    int l = threadIdx.x & 31;      // lane in group: dims l*8 .. l*8+7
    int i = blockIdx.x * 8 + wg;
    if (i >= n) return;

    const char* Hb = (const char*)H;
    int doff = l * 16;

    auto cvt = [](bf16x4 v) -> f32x4 {
        f32x4 r;
        #pragma unroll
        for (int j = 0; j < 4; j++) r[j] = (float)v[j];
        return r;
    };
    auto lo4 = [](bf16x8 v) -> bf16x4 { return __builtin_shufflevector(v, v, 0, 1, 2, 3); };
    auto hi4 = [](bf16x8 v) -> bf16x4 { return __builtin_shufflevector(v, v, 4, 5, 6, 7); };

    float dii = dinv[i];
    bf16x8 selfv = *(const bf16x8*)(Hb + ((size_t)i << 9) + doff);
    f32x4 acc0 = cvt(lo4(selfv)) * (dii * dii);
    f32x4 acc1 = cvt(hi4(selfv)) * (dii * dii);

    int e0 = offsets[i], e1 = offsets[i + 1];
    int e = e0;
    for (; e + 8 <= e1; e += 8) {
        unsigned s[8]; float w[8];
        #pragma unroll
        for (int j = 0; j < 8; j++) {
            int2 t = csr_e[e + j];
            s[j] = min((unsigned)t.x, (unsigned)(NNODES - 1));
            w[j] = __int_as_float(t.y);
        }
        bf16x8 h[8];
        #pragma unroll
        for (int j = 0; j < 8; j++) {
            h[j] = *(const bf16x8*)(Hb + ((size_t)s[j] << 9) + doff);
        }
        __builtin_amdgcn_sched_barrier(0);   // all 8 gathers issued before any consume
        #pragma unroll
        for (int j = 0; j < 8; j++) {
            acc0 += cvt(lo4(h[j])) * w[j];
            acc1 += cvt(hi4(h[j])) * w[j];
        }
    }
    if (e < e1) {
        bf16x8 z;
        #pragma unroll
        for (int q = 0; q < 8; q++) z[q] = (bf16_t)0.0f;
        unsigned s[8]; float w[8]; bool val[8];
        #pragma unroll
        for (int j = 0; j < 8; j++) {
            bool valid = (e + j) < e1;
            val[j] = valid;
            int2 t = csr_e[valid ? e + j : e];   // e < e1 so csr_e[e] is safe
            s[j] = min((unsigned)t.x, (unsigned)(NNODES - 1));
            w[j] = valid ? __int_as_float(t.y) : 0.0f;
        }
        bf16x8 h[8];
        #pragma unroll
        for (int j = 0; j < 8; j++) {
            h[j] = z;
            if (val[j]) h[j] = *(const bf16x8*)(Hb + ((size_t)s[j] << 9) + doff);
        }
        __builtin_amdgcn_sched_barrier(0);
        #pragma unroll
        for (int j = 0; j < 8; j++) {
            acc0 += cvt(lo4(h[j])) * w[j];
            acc1 += cvt(hi4(h[j])) * w[j];
        }
    }

    const f32x4* bp = (const f32x4*)(bias + l * 8);
    acc0 += bp[0];
    acc1 += bp[1];
    #pragma unroll
    for (int j = 0; j < 4; j++) {
        acc0[j] = fmaxf(acc0[j], 0.0f);
        acc1[j] = fmaxf(acc1[j], 0.0f);
    }

    if (OUT_BF16) {
        bf16x8 o;
        #pragma unroll
        for (int j = 0; j < 4; j++) { o[j] = (bf16_t)acc0[j]; o[j + 4] = (bf16_t)acc1[j]; }
        *(bf16x8*)((bf16_t*)outv + (size_t)i * DIM + l * 8) = o;
    } else {
        float* op = (float*)outv + (size_t)i * DIM + l * 8;
        *(f32x4*)op = acc0;
        *(f32x4*)(op + 4) = acc1;
    }
}

// ---------------- launch ----------------

extern "C" void kernel_launch(void* const* d_in, const int* in_sizes, int n_in,
                              void* d_out, int out_size, void* d_ws, size_t ws_size,
                              hipStream_t stream) {
    const float* x  = (const float*)d_in[0];
    const int*   ei = (const int*)d_in[1];
    const float* W1 = (const float*)d_in[2];
    const float* b1 = (const float*)d_in[3];
    const float* W2 = (const float*)d_in[4];
    const float* b2 = (const float*)d_in[5];
    float* out = (float*)d_out;

    const int n = NNODES;
    const int E = in_sizes[1] / 2;
    const int nb = (n + 255) / 256;            // 196

    char* ws = (char*)d_ws;
    size_t off = 0;
    auto alloc = [&](size_t bytes) -> char* {
        char* p = ws + off;
        off += (bytes + 255) & ~(size_t)255;
        return p;
    };
    float*  dinv     = (float*)alloc((size_t)n * 4);
    int*    counts   = (int*)alloc((size_t)n * 4);
    int*    offsets  = (int*)alloc((size_t)(n + 1) * 4);
    int*    cursor   = (int*)alloc((size_t)n * 4);
    int2*   csr_e    = (int2*)alloc((size_t)E * 8);
    bf16_t* Wf1      = (bf16_t*)alloc((size_t)DIM * DIM * 2);
    bf16_t* Wf2      = (bf16_t*)alloc((size_t)DIM * DIM * 2);
    bf16_t* P        = (bf16_t*)alloc((size_t)n * DIM * 2);   // GEMM output (bf16, row-major)
    bf16_t* X2       = (bf16_t*)alloc((size_t)n * DIM * 2);   // inter-layer activation (bf16)

    int tiles = (n + 15) / 16;                 // 3125 (exact: 50000 = 16*3125)
    int gemm_blocks = (tiles + 3) / 4;         // 782
    int hist_blocks = (E + 255) / 256;         // 1563
    int agg_blocks = (n + 7) / 8;              // 6250

    // 1: zero counts + convert both W
    prep_kernel<<<nb + 512, 256, 0, stream>>>(counts, W1, W2, Wf1, Wf2, n);
    // 2: GEMM layer 1 (double-buffered) with hist fused in its shadow
    gemm1_hist_kernel<<<gemm_blocks + hist_blocks, 256, 0, stream>>>(x, Wf1, P, tiles,
                                                                     gemm_blocks, ei, E, counts);
    // 3-4: scan, scatter
    scan_kernel<<<nb, 256, 0, stream>>>(counts, offsets, cursor, dinv, n);
    scatter_kernel<<<hist_blocks, 256, 0, stream>>>(ei, E, dinv, cursor, csr_e);
    // 5-7: agg1, gemm2, agg2
    aggregate_kernel<1><<<agg_blocks, 256, 0, stream>>>(P, offsets, csr_e, dinv, b1, X2, n);
    gemm2_kernel<<<gemm_blocks, 256, 0, stream>>>(X2, Wf2, P, tiles);
    aggregate_kernel<0><<<agg_blocks, 256, 0, stream>>>(P, offsets, csr_e, dinv, b2, out, n);
}

// Round 13
// 246.085 us; speedup vs baseline: 1.2632x; 1.0218x over previous
//
#include <hip/hip_runtime.h>
#include <stdint.h>

typedef __bf16 bf16_t;
typedef bf16_t bf16x4 __attribute__((ext_vector_type(4)));
typedef bf16_t bf16x8 __attribute__((ext_vector_type(8)));
typedef float f32x4 __attribute__((ext_vector_type(4)));

#define DIM 256
#define NNODES 50000

// ---------------- edge dtype detection (int64 vs int32), per-wave inline ----------------
__device__ __forceinline__ int detect_f64(const int* __restrict__ ei) {
    int v = ei[2 * (threadIdx.x & 63) + 1];
    unsigned long long m = __ballot(v == 0);
    return __popcll(m) > 32;
}

__device__ __forceinline__ int load_edge(const int* __restrict__ ei, int E, int f64,
                                         int which /*0=src,1=dst*/, int e) {
    int v = f64 ? ei[(size_t)which * 2 * E + 2 * (size_t)e]   // int64 low word (LE)
                : ei[(size_t)which * E + (size_t)e];
    return min(max(v, 0), NNODES - 1);
}

// ---------------- prep: zero counts + convert W (fp32 -> fragment-order bf16) ----------
// Wf layout: slice s=k>>5; frag f=nt*64+quad*16+m; flat short index s*8192+f*8+j.
__global__ __launch_bounds__(256) void prep_kernel(int* __restrict__ counts,
                                                   const float* __restrict__ W1,
                                                   const float* __restrict__ W2,
                                                   bf16_t* __restrict__ Wf1,
                                                   bf16_t* __restrict__ Wf2, int n) {
    const int nb = (NNODES + 255) / 256;   // 196
    int b = blockIdx.x, t = threadIdx.x;
    if (b < nb) {
        int idx = b * 256 + t;
        if (idx < n) counts[idx] = 0;
    } else {
        int cw = b - nb;                   // 0..511
        const float* W = (cw & 256) ? W2 : W1;
        bf16_t* Wf = (cw & 256) ? Wf2 : Wf1;
        int k = cw & 255;
        int s = k >> 5, quad = (k >> 3) & 3, j = k & 7;
        int nt = t >> 4, m = t & 15;
        Wf[s * 8192 + (nt * 64 + quad * 16 + m) * 8 + j] = (bf16_t)W[k * DIM + t];
    }
}

// ---------------- one-dispatch scan, zero synchronization (r9, passed) ----------------
__global__ __launch_bounds__(256) void scan_kernel(const int* __restrict__ counts,
                                                   int* __restrict__ offsets,
                                                   int* __restrict__ cursor,
                                                   float* __restrict__ dinv, int n) {
    __shared__ int red[256];
    __shared__ int sm[256];
    int b = blockIdx.x, t = threadIdx.x;

    int part = 0;
    const int4* c4 = (const int4*)counts;
    int lim = b * 64;
    for (int j = t; j < lim; j += 256) {
        int4 v = c4[j];
        part += v.x + v.y + v.z + v.w;
    }
    red[t] = part;
    __syncthreads();
    #pragma unroll
    for (int off = 128; off > 0; off >>= 1) {
        if (t < off) red[t] += red[t + off];
        __syncthreads();
    }
    int base = red[0];

    int idx = b * 256 + t;
    int v = (idx < n) ? counts[idx] : 0;
    sm[t] = v;
    __syncthreads();
    #pragma unroll
    for (int off = 1; off < 256; off <<= 1) {
        int u = (t >= off) ? sm[t - off] : 0;
        __syncthreads();
        sm[t] += u;
        __syncthreads();
    }
    if (idx < n) {
        int incl = base + sm[t];
        offsets[idx + 1] = incl;
        cursor[idx] = incl - v;
        dinv[idx] = rsqrtf((float)(v + 1));  // +1 self-loop
    }
    if (idx == 0) offsets[0] = 0;
}

// ---------------- scatter (standalone) ----------------
__global__ void scatter_kernel(const int* __restrict__ ei, int E,
                               const float* __restrict__ dinv, int* __restrict__ cursor,
                               int2* __restrict__ csr_e) {
    int f64 = detect_f64(ei);
    int e = blockIdx.x * blockDim.x + threadIdx.x;
    if (e < E) {
        int s = load_edge(ei, E, f64, 0, e);
        int d = load_edge(ei, E, f64, 1, e);
        int pos = atomicAdd(&cursor[d], 1);
        if (pos >= 0 && pos < E) {
            int2 v;
            v.x = s;
            v.y = __float_as_int(dinv[s] * dinv[d]);
            csr_e[pos] = v;
        }
    }
}

// ---------------- GEMM body: 1 tile/wave + global_load_lds dbuf staging (m97 pattern) ----
// Staging via __builtin_amdgcn_global_load_lds width=16 (guide Common-mistake #1: hipcc
// never auto-emits it; m93->m97 = +67% on a staging-bound MFMA loop). Per slice each wave
// issues 4 async 1KB copies (LDS dest = wave-uniform base, linear layout), double-buffered,
// ONE barrier per slice. No VGPR staging round-trip at all.
template <bool F32A>
__device__ __forceinline__ void gemm_body(const void* __restrict__ Xv,
                                          const bf16_t* __restrict__ Wf,
                                          bf16_t* __restrict__ H, int tiles, int bid,
                                          bf16_t* sB /*[2][8192]*/) {
    int tid = threadIdx.x;
    int wave = tid >> 6, lane = tid & 63;
    int m = lane & 15, quad = lane >> 4;
    int tile = bid * 4 + wave;
    bool active = tile < tiles;
    int arow = (min(tile, tiles - 1)) * 16 + m;

    f32x4 acc[16] = {};

    auto stage = [&](int s, int buf) {
        const char* g = (const char*)Wf + s * 16384 + wave * 4096 + lane * 16;
        char* l = (char*)sB + buf * 16384 + wave * 4096;   // wave-uniform; HW adds lane*16
        #pragma unroll
        for (int it = 0; it < 4; it++) {
            __builtin_amdgcn_global_load_lds(
                (const __attribute__((address_space(1))) void*)(g + it * 1024),
                (__attribute__((address_space(3))) void*)(l + it * 1024), 16, 0, 0);
        }
    };

    stage(0, 0);
    __syncthreads();                          // drains prologue staging (vmcnt 0 + barrier)

    for (int s = 0; s < 8; s++) {
        int cur = s & 1;
        if (s < 7) stage(s + 1, cur ^ 1);     // async: flies under this slice's compute

        // A fragment: A[m][k = s*32 + quad*8 + j]
        bf16x8 a;
        if (F32A) {
            const f32x4* xp = (const f32x4*)((const float*)Xv + (size_t)arow * DIM + s * 32 + quad * 8);
            f32x4 x0 = xp[0], x1 = xp[1];
            #pragma unroll
            for (int j = 0; j < 4; j++) { a[j] = (bf16_t)x0[j]; a[j + 4] = (bf16_t)x1[j]; }
        } else {
            a = *(const bf16x8*)((const bf16_t*)Xv + (size_t)arow * DIM + s * 32 + quad * 8);
        }

        const bf16_t* bs = sB + cur * 8192;
        #pragma unroll
        for (int nt = 0; nt < 16; nt++) {
            bf16x8 b = *(const bf16x8*)(bs + nt * 512 + lane * 8);  // sequential: no conflicts
            acc[nt] = __builtin_amdgcn_mfma_f32_16x16x32_bf16(a, b, acc[nt], 0, 0, 0);
        }

        __syncthreads();                      // one barrier/slice: staging done + reads done
    }

    if (active) {
        int rowb = tile * 16 + quad * 4;
        #pragma unroll
        for (int nt = 0; nt < 16; nt++) {
            #pragma unroll
            for (int r = 0; r < 4; r++) {
                H[(size_t)(rowb + r) * DIM + nt * 16 + m] = (bf16_t)acc[nt][r];
            }
        }
    }
}

// ---------------- GEMM1 (fp32 A) + hist fused ----------------
__global__ __launch_bounds__(256, 4) void gemm1_hist_kernel(const float* __restrict__ X,
                                                            const bf16_t* __restrict__ Wf,
                                                            bf16_t* __restrict__ H, int tiles,
                                                            int gemm_blocks,
                                                            const int* __restrict__ ei, int E,
                                                            int* __restrict__ counts) {
    __shared__ bf16_t sB[2 * 8192];
    if ((int)blockIdx.x >= gemm_blocks) {
        int f64 = detect_f64(ei);
        int e = (blockIdx.x - gemm_blocks) * 256 + threadIdx.x;
        if (e < E) atomicAdd(&counts[load_edge(ei, E, f64, 1, e)], 1);
        return;
    }
    gemm_body<true>(X, Wf, H, tiles, blockIdx.x, sB);
}

// ---------------- GEMM layer 2 (bf16 A) ----------------
__global__ __launch_bounds__(256, 4) void gemm2_kernel(const bf16_t* __restrict__ Xv,
                                                       const bf16_t* __restrict__ Wf,
                                                       bf16_t* __restrict__ H, int tiles) {
    __shared__ bf16_t sB[2 * 8192];
    gemm_body<false>(Xv, Wf, H, tiles, blockIdx.x, sB);
}

// ---------------- Aggregation (r10/r12: 8-deep fenced gathers, masked tail) --------------
// At the measured VMEM-return roofline: 260MB delivered / 40.3us = 6.45 TB/s (m13 ceiling).
template <int OUT_BF16>
__global__ __launch_bounds__(256) void aggregate_kernel(const bf16_t* __restrict__ H,
                                                        const int* __restrict__ offsets,
                                                        const int2* __restrict__ csr_e,
                                                        const float* __restrict__ dinv,
                                                        const float* __restrict__ bias,
                                                        void* __restrict__ outv, int n) {
    int wg = threadIdx.x >> 5;     // 8 node-groups per block
    int l = threadIdx.x & 31;      // lane in group: dims l*8 .. l*8+7
    int i = blockIdx.x * 8 + wg;
    if (i >= n) return;

    const char* Hb = (const char*)H;
    int doff = l * 16;

    auto cvt = [](bf16x4 v) -> f32x4 {
        f32x4 r;
        #pragma unroll
        for (int j = 0; j < 4; j++) r[j] = (float)v[j];
        return r;
    };
    auto lo4 = [](bf16x8 v) -> bf16x4 { return __builtin_shufflevector(v, v, 0, 1, 2, 3); };
    auto hi4 = [](bf16x8 v) -> bf16x4 { return __builtin_shufflevector(v, v, 4, 5, 6, 7); };

    float dii = dinv[i];
    bf16x8 selfv = *(const bf16x8*)(Hb + ((size_t)i << 9) + doff);
    f32x4 acc0 = cvt(lo4(selfv)) * (dii * dii);
    f32x4 acc1 = cvt(hi4(selfv)) * (dii * dii);

    int e0 = offsets[i], e1 = offsets[i + 1];
    int e = e0;
    for (; e + 8 <= e1; e += 8) {
        unsigned s[8]; float w[8];
        #pragma unroll
        for (int j = 0; j < 8; j++) {
            int2 t = csr_e[e + j];
            s[j] = min((unsigned)t.x, (unsigned)(NNODES - 1));
            w[j] = __int_as_float(t.y);
        }
        bf16x8 h[8];
        #pragma unroll
        for (int j = 0; j < 8; j++) {
            h[j] = *(const bf16x8*)(Hb + ((size_t)s[j] << 9) + doff);
        }
        __builtin_amdgcn_sched_barrier(0);   // all 8 gathers issued before any consume
        #pragma unroll
        for (int j = 0; j < 8; j++) {
            acc0 += cvt(lo4(h[j])) * w[j];
            acc1 += cvt(hi4(h[j])) * w[j];
        }
    }
    if (e < e1) {
        bf16x8 z;
        #pragma unroll
        for (int q = 0; q < 8; q++) z[q] = (bf16_t)0.0f;
        unsigned s[8]; float w[8]; bool val[8];
        #pragma unroll
        for (int j = 0; j < 8; j++) {
            bool valid = (e + j) < e1;
            val[j] = valid;
            int2 t = csr_e[valid ? e + j : e];   // e < e1 so csr_e[e] is safe
            s[j] = min((unsigned)t.x, (unsigned)(NNODES - 1));
            w[j] = valid ? __int_as_float(t.y) : 0.0f;
        }
        bf16x8 h[8];
        #pragma unroll
        for (int j = 0; j < 8; j++) {
            h[j] = z;
            if (val[j]) h[j] = *(const bf16x8*)(Hb + ((size_t)s[j] << 9) + doff);
        }
        __builtin_amdgcn_sched_barrier(0);
        #pragma unroll
        for (int j = 0; j < 8; j++) {
            acc0 += cvt(lo4(h[j])) * w[j];
            acc1 += cvt(hi4(h[j])) * w[j];
        }
    }

    const f32x4* bp = (const f32x4*)(bias + l * 8);
    acc0 += bp[0];
    acc1 += bp[1];
    #pragma unroll
    for (int j = 0; j < 4; j++) {
        acc0[j] = fmaxf(acc0[j], 0.0f);
        acc1[j] = fmaxf(acc1[j], 0.0f);
    }

    if (OUT_BF16) {
        bf16x8 o;
        #pragma unroll
        for (int j = 0; j < 4; j++) { o[j] = (bf16_t)acc0[j]; o[j + 4] = (bf16_t)acc1[j]; }
        *(bf16x8*)((bf16_t*)outv + (size_t)i * DIM + l * 8) = o;
    } else {
        float* op = (float*)outv + (size_t)i * DIM + l * 8;
        *(f32x4*)op = acc0;
        *(f32x4*)(op + 4) = acc1;
    }
}

// ---------------- launch ----------------

extern "C" void kernel_launch(void* const* d_in, const int* in_sizes, int n_in,
                              void* d_out, int out_size, void* d_ws, size_t ws_size,
                              hipStream_t stream) {
    const float* x  = (const float*)d_in[0];
    const int*   ei = (const int*)d_in[1];
    const float* W1 = (const float*)d_in[2];
    const float* b1 = (const float*)d_in[3];
    const float* W2 = (const float*)d_in[4];
    const float* b2 = (const float*)d_in[5];
    float* out = (float*)d_out;

    const int n = NNODES;
    const int E = in_sizes[1] / 2;
    const int nb = (n + 255) / 256;            // 196

    char* ws = (char*)d_ws;
    size_t off = 0;
    auto alloc = [&](size_t bytes) -> char* {
        char* p = ws + off;
        off += (bytes + 255) & ~(size_t)255;
        return p;
    };
    float*  dinv     = (float*)alloc((size_t)n * 4);
    int*    counts   = (int*)alloc((size_t)n * 4);
    int*    offsets  = (int*)alloc((size_t)(n + 1) * 4);
    int*    cursor   = (int*)alloc((size_t)n * 4);
    int2*   csr_e    = (int2*)alloc((size_t)E * 8);
    bf16_t* Wf1      = (bf16_t*)alloc((size_t)DIM * DIM * 2);
    bf16_t* Wf2      = (bf16_t*)alloc((size_t)DIM * DIM * 2);
    bf16_t* P        = (bf16_t*)alloc((size_t)n * DIM * 2);   // GEMM output (bf16, row-major)
    bf16_t* X2       = (bf16_t*)alloc((size_t)n * DIM * 2);   // inter-layer activation (bf16)

    int tiles = (n + 15) / 16;                 // 3125 (exact: 50000 = 16*3125)
    int gemm_blocks = (tiles + 3) / 4;         // 782
    int hist_blocks = (E + 255) / 256;         // 1563
    int agg_blocks = (n + 7) / 8;              // 6250

    // 1: zero counts + convert both W
    prep_kernel<<<nb + 512, 256, 0, stream>>>(counts, W1, W2, Wf1, Wf2, n);
    // 2: GEMM layer 1 (global_load_lds dbuf) with hist fused in its shadow
    gemm1_hist_kernel<<<gemm_blocks + hist_blocks, 256, 0, stream>>>(x, Wf1, P, tiles,
                                                                     gemm_blocks, ei, E, counts);
    // 3-4: scan, scatter
    scan_kernel<<<nb, 256, 0, stream>>>(counts, offsets, cursor, dinv, n);
    scatter_kernel<<<hist_blocks, 256, 0, stream>>>(ei, E, dinv, cursor, csr_e);
    // 5-7: agg1, gemm2, agg2
    aggregate_kernel<1><<<agg_blocks, 256, 0, stream>>>(P, offsets, csr_e, dinv, b1, X2, n);
    gemm2_kernel<<<gemm_blocks, 256, 0, stream>>>(X2, Wf2, P, tiles);
    aggregate_kernel<0><<<agg_blocks, 256, 0, stream>>>(P, offsets, csr_e, dinv, b2, out, n);
}